// Round 4
// baseline (265.077 us; speedup 1.0000x reference)
//
#include <hip/hip_runtime.h>
#include <math.h>

#define B    32
#define CIN  128
#define NN   8192
#define N1   8190     // length after k=3 valid conv
#define N1P  8192     // padded row stride for h2
#define CH   10

// K0: transpose w1[o][ci][k] -> wT[ci][o*3+k] (rows padded to 32 floats)
// so k1's per-channel 30 weights are contiguous -> batched s_loads.
__global__ void k0_prep(const float* __restrict__ w1, float* __restrict__ wT)
{
    const int i = blockIdx.x * 256 + threadIdx.x;     // 0..4095
    if (i < CIN * 32) {
        const int ci = i >> 5, r = i & 31;
        float v = 0.f;
        if (r < 30) {
            const int o = r / 3, k = r - o * 3;
            v = w1[(o * CIN + ci) * 3 + k];
        }
        wT[i] = v;
    }
}

// K1: h2[b][o][t] = relu(b2 + W2 * relu(b1 + conv_k3(signal)))
// Barrier-free streaming: per-thread double-buffered 8-channel chunks,
// 24 independent dword loads in flight per buffer. No LDS.
__global__ __launch_bounds__(256) void k1_conv12(
    const float* __restrict__ sig, const float* __restrict__ wT, const float* __restrict__ b1,
    const float* __restrict__ w2, const float* __restrict__ b2, float* __restrict__ h2out)
{
    const int tid = threadIdx.x;
    const int b   = blockIdx.y;
    const int t   = blockIdx.x * 256 + tid;           // 0..8191
    const int tc  = (t < N1 - 1) ? t : (N1 - 1);      // clamp: loads stay in-bounds (tc+2 <= 8191)
    const float* sp = sig + (size_t)b * CIN * NN + tc;

    float y[CH];
#pragma unroll
    for (int o = 0; o < CH; ++o) y[o] = b1[o];

    float ax[8], ay[8], az[8];                        // buffer A
    float bx[8], by[8], bz[8];                        // buffer B

    auto load = [&](float* x0, float* x1, float* x2, int c) {
#pragma unroll
        for (int j = 0; j < 8; ++j) {
            const float* p = sp + (size_t)(c * 8 + j) * NN;
            x0[j] = p[0]; x1[j] = p[1]; x2[j] = p[2];
        }
    };
    auto comp = [&](const float* x0, const float* x1, const float* x2, int c) {
        const float* wbase = wT + c * 8 * 32;
#pragma unroll
        for (int j = 0; j < 8; ++j) {
            const float* wrow = wbase + j * 32;       // 30 contiguous, wave-uniform
#pragma unroll
            for (int o = 0; o < CH; ++o) {
                y[o] = fmaf(wrow[o * 3 + 0], x0[j], y[o]);
                y[o] = fmaf(wrow[o * 3 + 1], x1[j], y[o]);
                y[o] = fmaf(wrow[o * 3 + 2], x2[j], y[o]);
            }
        }
    };

    load(ax, ay, az, 0);
    for (int c = 0; c < 16; c += 2) {                 // 16 chunks of 8 channels
        load(bx, by, bz, c + 1);                      // B in flight while computing A
        comp(ax, ay, az, c);
        if (c + 2 < 16) load(ax, ay, az, c + 2);      // A in flight while computing B
        comp(bx, by, bz, c + 1);
    }

    if (t < N1) {
#pragma unroll
        for (int o = 0; o < CH; ++o) y[o] = fmaxf(y[o], 0.f);
#pragma unroll
        for (int o = 0; o < CH; ++o) {
            float a = b2[o];
#pragma unroll
            for (int i = 0; i < CH; ++i) a = fmaf(w2[o * CH + i], y[i], a);
            h2out[((size_t)b * CH + o) * N1P + t] = fmaxf(a, 0.f);
        }
    }
}

// K2: convT(k=3)+relu+1x1+sigmoid directly from global (h2 tile is L1/L2-hot),
// lr exchanged through small LDS arrays (one barrier), then tridiag + log.
__global__ __launch_bounds__(256) void k2_fused(
    const float* __restrict__ h2, const float* __restrict__ cd,
    const float* __restrict__ wt, const float* __restrict__ bt,
    const float* __restrict__ w3, const float* __restrict__ b3,
    const float* __restrict__ cstp, float* __restrict__ outv, float* __restrict__ bsums)
{
    __shared__ float lsh[260], rsh[260];
    __shared__ float red[256];
    const int tid = threadIdx.x;
    const int b   = blockIdx.y;
    const int t0  = blockIdx.x * 256;
    const float* hb = h2 + (size_t)b * CH * N1P;

    auto computeLR = [&](int sidx) {                  // s = t0 + sidx, caller guarantees s < NN
        const int s = t0 + sidx;
        float acc[CH];
#pragma unroll
        for (int o = 0; o < CH; ++o) acc[o] = bt[o];
#pragma unroll
        for (int i = 0; i < CH; ++i) {
            const float* hp = hb + (size_t)i * N1P;
            const float v0 = (s < N1)            ? hp[s]     : 0.f;
            const float v1 = (s >= 1 && s <= N1) ? hp[s - 1] : 0.f;
            const float v2 = (s >= 2)            ? hp[s - 2] : 0.f;
            const float* wp = wt + i * CH * 3;        // 30 contiguous, wave-uniform
#pragma unroll
            for (int o = 0; o < CH; ++o) {
                acc[o] = fmaf(wp[o * 3 + 0], v0, acc[o]);
                acc[o] = fmaf(wp[o * 3 + 1], v1, acc[o]);
                acc[o] = fmaf(wp[o * 3 + 2], v2, acc[o]);
            }
        }
        float l = b3[0], r = b3[1];
#pragma unroll
        for (int o = 0; o < CH; ++o) {
            const float h3 = fmaxf(acc[o], 0.f);
            l = fmaf(w3[o],      h3, l);
            r = fmaf(w3[CH + o], h3, r);
        }
        lsh[sidx] = 1.f / (1.f + __expf(-l));
        rsh[sidx] = 1.f / (1.f + __expf(-r));
    };

    computeLR(tid);
    if (tid < 3 && t0 + 256 + tid < NN) computeLR(256 + tid);  // halo s = t0+256..t0+258
    __syncthreads();

    const int t = t0 + tid;
    float v = 0.f;
    if (t < N1) {
        const float c0 = cd[(size_t)b * (NN - 1) + t];
        const float c1 = cd[(size_t)b * (NN - 1) + t + 1];
        const float mi = c1 * rsh[tid + 1] + c0 * lsh[tid + 1];
        const float mo = rsh[tid] + lsh[tid + 2];
        v = __logf(cstp[0] * mi / mo);
        outv[(size_t)b * N1 + t] = v;
    }

    red[tid] = v;
    __syncthreads();
#pragma unroll
    for (int s = 128; s > 0; s >>= 1) {
        if (tid < s) red[tid] += red[tid + s];
        __syncthreads();
    }
    if (tid == 0) bsums[blockIdx.y * gridDim.x + blockIdx.x] = red[0];
}

// K3: fused mean + subtract. Every block redundantly reduces the 1024 bsums
// (4 KB, L2-hot), then subtracts the mean from its 256-element slice.
__global__ __launch_bounds__(256) void k3_meansub(
    const float* __restrict__ bsums, float* __restrict__ outv, int n)
{
    __shared__ float red[256];
    const int tid = threadIdx.x;
    float s = 0.f;
#pragma unroll
    for (int i = 0; i < 4; ++i) s += bsums[tid + i * 256];
    red[tid] = s;
    __syncthreads();
#pragma unroll
    for (int st = 128; st > 0; st >>= 1) {
        if (tid < st) red[tid] += red[tid + st];
        __syncthreads();
    }
    const float mean = red[0] / (float)(B * N1);      // all lanes read red[0] after barrier
    __syncthreads();
    const int i = blockIdx.x * 256 + tid;
    if (i < n) outv[i] -= mean;
}

extern "C" void kernel_launch(void* const* d_in, const int* in_sizes, int n_in,
                              void* d_out, int out_size, void* d_ws, size_t ws_size,
                              hipStream_t stream)
{
    const float* sig = (const float*)d_in[0];
    const float* cd  = (const float*)d_in[1];
    // d_in[2] = index_diag (1 for these shapes)
    const float* w1  = (const float*)d_in[3];
    const float* b1  = (const float*)d_in[4];
    const float* w2  = (const float*)d_in[5];
    const float* b2  = (const float*)d_in[6];
    const float* wt  = (const float*)d_in[7];
    const float* bt  = (const float*)d_in[8];
    const float* w3  = (const float*)d_in[9];
    const float* b3  = (const float*)d_in[10];
    const float* cst = (const float*)d_in[11];

    float* outv = (float*)d_out;

    // workspace layout (floats)
    float* ws   = (float*)d_ws;
    float* wT   = ws;                          // CIN*32 = 4096
    float* h2   = wT + CIN * 32;               // B*CH*N1P = 2,621,440
    float* bsum = h2 + (size_t)B * CH * N1P;   // 1024

    dim3 blk(256);
    dim3 g1(32, B);                            // 32 t-tiles x 32 batch

    k0_prep   <<<dim3(16), blk, 0, stream>>>(w1, wT);
    k1_conv12 <<<g1, blk, 0, stream>>>(sig, wT, b1, w2, b2, h2);
    k2_fused  <<<g1, blk, 0, stream>>>(h2, cd, wt, bt, w3, b3, cst, outv, bsum);
    k3_meansub<<<dim3((out_size + 255) / 256), blk, 0, stream>>>(bsum, outv, out_size);
}

// Round 5
// 243.753 us; speedup vs baseline: 1.0875x; 1.0875x over previous
//
#include <hip/hip_runtime.h>
#include <math.h>

#define B     32
#define CIN   128
#define NN    8192
#define N1    8190     // output length after k=3 valid conv
#define CH    10
#define TOUT  252      // diag outputs per block (h2 tile = TOUT+4 = 256 cols, 1/thread)
#define NTILE 33       // ceil(8190/252)

// K0: transpose w1[o][ci][k] -> wT[ci][o*3+k] (rows padded to 32 floats)
// so k_main's per-channel 30 weights are contiguous wave-uniform s_loads.
__global__ void k0_prep(const float* __restrict__ w1, float* __restrict__ wT)
{
    const int i = blockIdx.x * 256 + threadIdx.x;     // 0..4095
    if (i < CIN * 32) {
        const int ci = i >> 5, r = i & 31;
        float v = 0.f;
        if (r < 30) {
            const int o = r / 3, k = r - o * 3;
            v = w1[(o * CIN + ci) * 3 + k];
        }
        wT[i] = v;
    }
}

// K_MAIN: whole pipeline per 252-output tile.
// Phase 1 (barrier-free streaming): thread computes h2 for one column
//   g = t0-2+tid via 8 chunks x 16 channels, one dwordx4 per channel.
// Phase 2 (LDS): convT(k=3)+relu+1x1+sigmoid -> lr; tridiag+log; block sum.
__global__ __launch_bounds__(256, 4) void k_main(
    const float* __restrict__ sig, const float* __restrict__ wT,
    const float* __restrict__ b1, const float* __restrict__ w2, const float* __restrict__ b2,
    const float* __restrict__ wt, const float* __restrict__ bt,
    const float* __restrict__ w3, const float* __restrict__ b3,
    const float* __restrict__ cd, const float* __restrict__ cstp,
    float* __restrict__ outv, float* __restrict__ bsums)
{
    __shared__ float h2s[CH * 256];    // 10240 B  [o][col]
    __shared__ float lsh[256], rsh[256];
    __shared__ float red[256];

    const int tid = threadIdx.x;
    const int b   = blockIdx.y;
    const int t0  = blockIdx.x * TOUT;
    const int g   = t0 - 2 + tid;                     // h2 column of this thread
    const bool gvalid = (g >= 0) && (g < N1);
    const bool sh = (g > NN - 4);                     // only g==8189 among valid cols
    int gl = (g < 0) ? 0 : g;
    if (gl > NN - 4) gl = NN - 4;                     // float4 [gl..gl+3] always in-bounds
    const float* sb = sig + (size_t)b * CIN * NN + gl;

    float y[CH];
#pragma unroll
    for (int o = 0; o < CH; ++o) y[o] = b1[o];

    for (int c = 0; c < 8; ++c) {                     // 8 chunks x 16 channels
        float4 v[16];
#pragma unroll
        for (int j = 0; j < 16; ++j)
            v[j] = *(const float4*)(sb + (size_t)(c * 16 + j) * NN);

        const float* wbase = wT + c * 16 * 32;
#pragma unroll
        for (int j = 0; j < 16; ++j) {
            const float s0 = sh ? v[j].y : v[j].x;    // signal[g]
            const float s1 = sh ? v[j].z : v[j].y;    // signal[g+1]
            const float s2 = sh ? v[j].w : v[j].z;    // signal[g+2]
            const float* wrow = wbase + j * 32;       // 30 contiguous uniform weights
#pragma unroll
            for (int o = 0; o < CH; ++o) {
                y[o] = fmaf(wrow[o * 3 + 0], s0, y[o]);
                y[o] = fmaf(wrow[o * 3 + 1], s1, y[o]);
                y[o] = fmaf(wrow[o * 3 + 2], s2, y[o]);
            }
        }
    }

    // conv2 (1x1) + relu -> LDS (zero outside [0,N1) for convT zero-padding)
#pragma unroll
    for (int o = 0; o < CH; ++o) y[o] = fmaxf(y[o], 0.f);
#pragma unroll
    for (int o = 0; o < CH; ++o) {
        float a = b2[o];
#pragma unroll
        for (int i = 0; i < CH; ++i) a = fmaf(w2[o * CH + i], y[i], a);
        h2s[o * 256 + tid] = gvalid ? fmaxf(a, 0.f) : 0.f;
    }
    __syncthreads();

    // convT + relu + 1x1 + sigmoid -> lr at s = t0 + tid (tid < 254)
    const int s = t0 + tid;
    if (tid < 254 && s < NN) {
        float acc[CH];
#pragma unroll
        for (int o = 0; o < CH; ++o) acc[o] = bt[o];
#pragma unroll
        for (int i = 0; i < CH; ++i) {
            const float a0 = h2s[i * 256 + tid];      // h2[s-2]
            const float a1 = h2s[i * 256 + tid + 1];  // h2[s-1]
            const float a2 = h2s[i * 256 + tid + 2];  // h2[s]
            const float* wp = wt + i * CH * 3;        // contiguous uniform
#pragma unroll
            for (int o = 0; o < CH; ++o) {
                acc[o] = fmaf(wp[o * 3 + 0], a2, acc[o]);
                acc[o] = fmaf(wp[o * 3 + 1], a1, acc[o]);
                acc[o] = fmaf(wp[o * 3 + 2], a0, acc[o]);
            }
        }
        float l = b3[0], r = b3[1];
#pragma unroll
        for (int o = 0; o < CH; ++o) {
            const float h3 = fmaxf(acc[o], 0.f);
            l = fmaf(w3[o],      h3, l);
            r = fmaf(w3[CH + o], h3, r);
        }
        lsh[tid] = 1.f / (1.f + __expf(-l));
        rsh[tid] = 1.f / (1.f + __expf(-r));
    }
    __syncthreads();

    // tridiagonal update + log for t = t0 + tid (tid < TOUT)
    float vlog = 0.f;
    const int t = t0 + tid;
    if (tid < TOUT && t < N1) {
        const float c0 = cd[(size_t)b * (NN - 1) + t];
        const float c1 = cd[(size_t)b * (NN - 1) + t + 1];
        const float mi = c1 * rsh[tid + 1] + c0 * lsh[tid + 1];
        const float mo = rsh[tid] + lsh[tid + 2];
        vlog = __logf(cstp[0] * mi / mo);
        outv[(size_t)b * N1 + t] = vlog;
    }

    red[tid] = vlog;
    __syncthreads();
#pragma unroll
    for (int st = 128; st > 0; st >>= 1) {
        if (tid < st) red[tid] += red[tid + st];
        __syncthreads();
    }
    if (tid == 0) bsums[blockIdx.y * NTILE + blockIdx.x] = red[0];
}

// K3: every block redundantly reduces the 1056 bsums (L2-hot), subtracts mean.
__global__ __launch_bounds__(256) void k3_meansub(
    const float* __restrict__ bsums, float* __restrict__ outv, int n)
{
    __shared__ float red[256];
    const int tid = threadIdx.x;
    float s = 0.f;
    for (int i = tid; i < NTILE * B; i += 256) s += bsums[i];
    red[tid] = s;
    __syncthreads();
#pragma unroll
    for (int st = 128; st > 0; st >>= 1) {
        if (tid < st) red[tid] += red[tid + st];
        __syncthreads();
    }
    const float mean = red[0] / (float)(B * N1);
    __syncthreads();
    const int i = blockIdx.x * 256 + tid;
    if (i < n) outv[i] -= mean;
}

extern "C" void kernel_launch(void* const* d_in, const int* in_sizes, int n_in,
                              void* d_out, int out_size, void* d_ws, size_t ws_size,
                              hipStream_t stream)
{
    const float* sig = (const float*)d_in[0];
    const float* cd  = (const float*)d_in[1];
    // d_in[2] = index_diag (1 for these shapes)
    const float* w1  = (const float*)d_in[3];
    const float* b1  = (const float*)d_in[4];
    const float* w2  = (const float*)d_in[5];
    const float* b2  = (const float*)d_in[6];
    const float* wt  = (const float*)d_in[7];
    const float* bt  = (const float*)d_in[8];
    const float* w3  = (const float*)d_in[9];
    const float* b3  = (const float*)d_in[10];
    const float* cst = (const float*)d_in[11];

    float* outv = (float*)d_out;

    // workspace layout (floats)
    float* ws   = (float*)d_ws;
    float* wT   = ws;                  // CIN*32 = 4096
    float* bsum = wT + CIN * 32;       // NTILE*B = 1056

    dim3 blk(256);

    k0_prep   <<<dim3(16), blk, 0, stream>>>(w1, wT);
    k_main    <<<dim3(NTILE, B), blk, 0, stream>>>(sig, wT, b1, w2, b2,
                                                   wt, bt, w3, b3, cd, cst, outv, bsum);
    k3_meansub<<<dim3((out_size + 255) / 256), blk, 0, stream>>>(bsum, outv, out_size);
}